// Round 8
// baseline (144.212 us; speedup 1.0000x reference)
//
#include <hip/hip_runtime.h>
#include <hip/hip_fp16.h>

constexpr int N = 50000;        // nodes
constexpr int D = 64;           // feature dim
constexpr int E = 1600000;      // edges
constexpr int NBUCK = (N + 127) / 128;   // 391 buckets of 128 nodes (dst>>7)
constexpr int CAP = 4608;                // bucket window capacity (mean 4092)
constexpr int BTHREADS = 1024;
constexpr int BBLOCKS = 256;             // verified round-7 config
constexpr int EPB = E / BBLOCKS;         // 6250 edges per block (exact)
constexpr int CPT = (EPB + BTHREADS - 1) / BTHREADS;  // 7

// ---------------------------------------------------------------------------
// K0: init per-bucket window cursors (cursor[b] = b*CAP)
__global__ void k_init(int* __restrict__ cursor) {
    int t = threadIdx.x;
    if (t < NBUCK) cursor[t] = t * CAP;
}

// K1: privatized counting-sort scatter -> fixed-capacity bucket windows.
// packed = dst<<16 | src (both < 65536); bucket = packed>>23.
// (verified round-7 version, unchanged)
__global__ __launch_bounds__(1024)
void k_bucket(const int* __restrict__ src, const int* __restrict__ dst,
              int* __restrict__ cursor, unsigned* __restrict__ packed) {
    __shared__ int lh[NBUCK];
    __shared__ int scanI[NBUCK];         // inclusive prefix over buckets
    __shared__ int wsum[16];             // 16 waves
    __shared__ int lb[NBUCK];
    __shared__ unsigned stage[EPB];      // 25 KB
    int tid = threadIdx.x;
    if (tid < NBUCK) lh[tid] = 0;
    __syncthreads();
    int base_e = blockIdx.x * EPB;
    unsigned pk[CPT];
    int bn[CPT], rk[CPT];
#pragma unroll
    for (int i = 0; i < CPT; ++i) {
        int idx = i * BTHREADS + tid;
        if (idx < EPB) {
            int e = base_e + idx;
            int d = dst[e];
            int s = src[e];
            bn[i] = d >> 7;
            pk[i] = ((unsigned)d << 16) | (unsigned)s;
            rk[i] = atomicAdd(&lh[bn[i]], 1);
        } else bn[i] = -1;
    }
    __syncthreads();
    // hierarchical inclusive scan of lh[0..NBUCK) into scanI
    int w = tid >> 6, l = tid & 63;
    int v = (tid < NBUCK) ? lh[tid] : 0;
    for (int off = 1; off < 64; off <<= 1) {
        int t = __shfl_up(v, off, 64);
        if (l >= off) v += t;
    }
    if (tid < NBUCK) scanI[tid] = v;
    if (l == 63) wsum[w] = v;
    __syncthreads();
    if (tid < 64) {                      // wave 0 scans the 16 wave sums
        int s = (tid < 16) ? wsum[tid] : 0;
        for (int off = 1; off < 16; off <<= 1) {
            int t = __shfl_up(s, off, 64);
            if (tid >= off) s += t;
        }
        if (tid < 16) wsum[tid] = s;
    }
    __syncthreads();
    if (tid < NBUCK && w > 0) scanI[tid] += wsum[w - 1];
    if (tid < NBUCK) {
        int c = lh[tid];
        lb[tid] = c ? atomicAdd(&cursor[tid], c) : 0;   // one global atomic/bucket/block
    }
    __syncthreads();
#pragma unroll
    for (int i = 0; i < CPT; ++i) {
        if (bn[i] >= 0) {
            int eb = (bn[i] == 0) ? 0 : scanI[bn[i] - 1];
            stage[eb + rk[i]] = pk[i];   // LDS scatter into bucket-sorted order
        }
    }
    __syncthreads();
    for (int j = tid; j < EPB; j += BTHREADS) {
        unsigned vv = stage[j];
        int bk = vv >> 23;               // dst>>7
        int eb = (bk == 0) ? 0 : scanI[bk - 1];
        packed[lb[bk] + (j - eb)] = vv;  // contiguous within each chunk
    }
}

// K2 (fused CSR + GEMM): one 1024-thr block per 128-node bucket.
// Phase A: single-pass counting sort (rank from histogram atomicAdd = stable
// slot, round-7 verified) -> csr/rowptr/rowend/norm. W-tile and x-tile loads
// are issued FIRST so their HBM latency hides under the sort.
// Phase B: 128x64 GEMM for this bucket's rows, norm taken from the in-LDS
// histogram (h2 numerics bitwise-identical to the old k_gemm: same fmaf
// chain per output). LDS 60.4 KB -> 2 blocks/CU; 391 blocks all co-resident
// in one dispatch wave (no tail).
__global__ __launch_bounds__(1024, 8)
void k_csrg(const int* __restrict__ cursor, const unsigned* __restrict__ packed,
            const float* __restrict__ x, const float* __restrict__ W,
            unsigned short* __restrict__ csr, int* __restrict__ rowptr,
            int* __restrict__ rowend, float* __restrict__ norm,
            __half* __restrict__ h2) {
    __shared__ int cnt[128];
    __shared__ int rowoff[128];            // exclusive prefix over 128 bins
    __shared__ unsigned short stage[CAP];  // 9 KB node-sorted src list
    __shared__ float Wl[64 * 64];          // 16 KB  Wl[k*64+d]
    __shared__ float xT[64 * 132];         // 33.8 KB xT[k*132+r] = x[base+r][k]
    int b = blockIdx.x, tid = threadIdx.x;
    if (tid < 128) cnt[tid] = 0;
    // --- issue W + x tile loads early (independent of sort phase) ---
    {
        const float4* W4 = (const float4*)W;
        ((float4*)Wl)[tid] = W4[tid];      // 1024 float4 = whole W
    }
    {
        int rr = tid >> 3;                 // 0..127
        int c0 = (tid & 7) * 8;            // 8 cols per thread
        int row = b * 128 + rr;
        if (row >= N) row = N - 1;         // clamp (stores guarded later)
        const float4* xr = (const float4*)(x + (size_t)row * 64 + c0);
        float4 v0 = xr[0];
        float4 v1 = xr[1];
        xT[(c0 + 0) * 132 + rr] = v0.x;
        xT[(c0 + 1) * 132 + rr] = v0.y;
        xT[(c0 + 2) * 132 + rr] = v0.z;
        xT[(c0 + 3) * 132 + rr] = v0.w;
        xT[(c0 + 4) * 132 + rr] = v1.x;
        xT[(c0 + 5) * 132 + rr] = v1.y;
        xT[(c0 + 6) * 132 + rr] = v1.z;
        xT[(c0 + 7) * 132 + rr] = v1.w;
    }
    __syncthreads();
    // --- phase A: single-pass counting sort of the bucket window ---
    int beg = b * CAP;
    int m = cursor[b] - beg;             // edges in this bucket (<= CAP)
    unsigned pk[5];
    int rk[5];
#pragma unroll
    for (int it = 0; it < 5; ++it) {     // ceil(CAP/1024) = 5
        int j = it * 1024 + tid;
        if (j < m) {
            unsigned p = packed[beg + j];
            pk[it] = p;
            rk[it] = atomicAdd(&cnt[(p >> 16) & 127], 1);   // rank = stable slot
        } else pk[it] = 0xFFFFFFFFu;     // sentinel: bucket bits impossible
    }
    __syncthreads();
    if (tid < 64) {                      // wave 0: 2 bins/lane inclusive scan
        int a = cnt[2 * tid], c1 = cnt[2 * tid + 1];
        int s = a + c1;
        for (int off = 1; off < 64; off <<= 1) {
            int t = __shfl_up(s, off, 64);
            if (tid >= off) s += t;
        }
        rowoff[2 * tid + 1] = s - c1;        // excl(2t+1)
        rowoff[2 * tid]     = s - c1 - a;    // excl(2t)
    }
    __syncthreads();
    if (tid < 128) {
        int excl = rowoff[tid];
        int node = b * 128 + tid;
        if (node < N) {
            rowptr[node] = beg + excl;
            rowend[node] = beg + excl + cnt[tid];
            norm[node] = cnt[tid] ? rsqrtf((float)cnt[tid]) : 0.0f;
        }
    }
    __syncthreads();
#pragma unroll
    for (int it = 0; it < 5; ++it) {
        int j = it * 1024 + tid;
        if (j < m)
            stage[rowoff[(pk[it] >> 16) & 127] + rk[it]] = (unsigned short)(pk[it] & 0xFFFFu);
    }
    __syncthreads();
    // csr copy-out (coalesced uint)
    {
        unsigned* du = (unsigned*)(csr + beg);  // beg even, base 4B-aligned
        const unsigned* su = (const unsigned*)stage;
        int mu = m >> 1;
        for (int k = tid; k < mu; k += 1024) du[k] = su[k];
        if ((m & 1) && tid == 0) csr[beg + m - 1] = stage[m - 1];
    }
    // --- phase B: 128x64 GEMM for this bucket's rows ---
    int tx = tid & 15;                   // cols tx*4 .. +3
    int ty = tid >> 4;                   // rows ty*2, ty*2+1  (0..63)
    float acc[2][4] = {};
#pragma unroll 8
    for (int k = 0; k < 64; ++k) {
        float2 xv = *(const float2*)&xT[k * 132 + ty * 2];
        float4 wv = *(const float4*)&Wl[k * 64 + tx * 4];
        acc[0][0] = fmaf(xv.x, wv.x, acc[0][0]);
        acc[0][1] = fmaf(xv.x, wv.y, acc[0][1]);
        acc[0][2] = fmaf(xv.x, wv.z, acc[0][2]);
        acc[0][3] = fmaf(xv.x, wv.w, acc[0][3]);
        acc[1][0] = fmaf(xv.y, wv.x, acc[1][0]);
        acc[1][1] = fmaf(xv.y, wv.y, acc[1][1]);
        acc[1][2] = fmaf(xv.y, wv.z, acc[1][2]);
        acc[1][3] = fmaf(xv.y, wv.w, acc[1][3]);
    }
#pragma unroll
    for (int i = 0; i < 2; ++i) {
        int r = ty * 2 + i;
        int row = b * 128 + r;
        if (row < N) {
            int dg = cnt[r];
            float nr = dg ? rsqrtf((float)dg) : 0.0f;
            __half2 p0 = __floats2half2_rn(acc[i][0] * nr, acc[i][1] * nr);
            __half2 p1 = __floats2half2_rn(acc[i][2] * nr, acc[i][3] * nr);
            __half2* dst2 = (__half2*)(h2 + (size_t)row * 64 + tx * 4);
            dst2[0] = p0;
            dst2[1] = p1;
        }
    }
}

// K3: fused aggregate + dst-norm + bias + softplus.
// One wave per node (12500 blocks x 4 waves = 50K waves of TLP — round-5
// proved fewer waves is 2x slower). (verified round-3 version, unchanged)
__global__ void k_aggregate(const int* __restrict__ rowptr, const int* __restrict__ rowend,
                            const unsigned short* __restrict__ csr,
                            const __half* __restrict__ h2, const float* __restrict__ norm,
                            const float* __restrict__ bias, float* __restrict__ out) {
    int node = blockIdx.x * 4 + (threadIdx.x >> 6);
    int lane = threadIdx.x & 63;
    int half = lane >> 5;          // which edge of the pair
    int fl = lane & 31;            // feature-pair index (features 2fl, 2fl+1)
    const __half2* h2v = (const __half2*)h2;   // row stride 32
    int beg = rowptr[node];
    int end = rowend[node];
    int deg = end - beg;
    int myidx = (beg + lane < end) ? (int)csr[beg + lane] : 0;
    int window = deg < 64 ? deg : 64;   // wave-uniform
    int npair = window >> 1;
    float ax = 0.0f, ay = 0.0f, bx = 0.0f, by = 0.0f;
    int p = 0;
    for (; p + 7 < npair; p += 8) {          // 16 edges per iteration, 8 loads in flight
        int s0 = __shfl(myidx, 2 * p + half, 64);
        int s1 = __shfl(myidx, 2 * p + 2 + half, 64);
        int s2 = __shfl(myidx, 2 * p + 4 + half, 64);
        int s3 = __shfl(myidx, 2 * p + 6 + half, 64);
        int s4 = __shfl(myidx, 2 * p + 8 + half, 64);
        int s5 = __shfl(myidx, 2 * p + 10 + half, 64);
        int s6 = __shfl(myidx, 2 * p + 12 + half, 64);
        int s7 = __shfl(myidx, 2 * p + 14 + half, 64);
        float2 v0 = __half22float2(h2v[s0 * 32 + fl]);
        float2 v1 = __half22float2(h2v[s1 * 32 + fl]);
        float2 v2 = __half22float2(h2v[s2 * 32 + fl]);
        float2 v3 = __half22float2(h2v[s3 * 32 + fl]);
        float2 v4 = __half22float2(h2v[s4 * 32 + fl]);
        float2 v5 = __half22float2(h2v[s5 * 32 + fl]);
        float2 v6 = __half22float2(h2v[s6 * 32 + fl]);
        float2 v7 = __half22float2(h2v[s7 * 32 + fl]);
        ax += (v0.x + v2.x) + (v4.x + v6.x);
        ay += (v0.y + v2.y) + (v4.y + v6.y);
        bx += (v1.x + v3.x) + (v5.x + v7.x);
        by += (v1.y + v3.y) + (v5.y + v7.y);
    }
    for (; p + 3 < npair; p += 4) {          // 8 edges per iteration
        int s0 = __shfl(myidx, 2 * p + half, 64);
        int s1 = __shfl(myidx, 2 * p + 2 + half, 64);
        int s2 = __shfl(myidx, 2 * p + 4 + half, 64);
        int s3 = __shfl(myidx, 2 * p + 6 + half, 64);
        float2 v0 = __half22float2(h2v[s0 * 32 + fl]);
        float2 v1 = __half22float2(h2v[s1 * 32 + fl]);
        float2 v2 = __half22float2(h2v[s2 * 32 + fl]);
        float2 v3 = __half22float2(h2v[s3 * 32 + fl]);
        ax += v0.x + v2.x;  ay += v0.y + v2.y;
        bx += v1.x + v3.x;  by += v1.y + v3.y;
    }
    for (; p < npair; ++p) {                 // pair tail (uniform trip count)
        int s = __shfl(myidx, 2 * p + half, 64);
        float2 v = __half22float2(h2v[s * 32 + fl]);
        ax += v.x;  ay += v.y;
    }
    if (window & 1) {                        // wave-uniform: all lanes shfl
        int s = __shfl(myidx, window - 1, 64);
        float2 v = __half22float2(h2v[s * 32 + fl]);
        if (half == 0) { ax += v.x;  ay += v.y; }
    }
    if (deg > 64) {                          // rare fallback, direct loads
        int j = beg + 64;
        for (; j + 1 < end; j += 2) {
            int s = csr[j + half];
            float2 v = __half22float2(h2v[s * 32 + fl]);
            ax += v.x;  ay += v.y;
        }
        if (j < end) {
            int s = csr[j];
            float2 v = __half22float2(h2v[s * 32 + fl]);
            if (half == 0) { ax += v.x;  ay += v.y; }
        }
    }
    ax += bx;  ay += by;
    ax += __shfl_xor(ax, 32, 64);            // combine the two half-waves
    ay += __shfl_xor(ay, 32, 64);
    if (half == 0) {
        float nrm = norm[node];
        float2 bs = ((const float2*)bias)[fl];
        float vx = ax * nrm + bs.x;
        float vy = ay * nrm + bs.y;
        float2 o;
        o.x = fmaxf(vx, 0.0f) + log1pf(expf(-fabsf(vx)));
        o.y = fmaxf(vy, 0.0f) + log1pf(expf(-fabsf(vy)));
        ((float2*)out)[node * 32 + fl] = o;
    }
}

extern "C" void kernel_launch(void* const* d_in, const int* in_sizes, int n_in,
                              void* d_out, int out_size, void* d_ws, size_t ws_size,
                              hipStream_t stream) {
    // inputs: t(f32,1), x(f32,N*D), weight(f32,D*D), bias(f32,D), src(i32,E), dst(i32,E)
    const float* x    = (const float*)d_in[1];
    const float* W    = (const float*)d_in[2];
    const float* bias = (const float*)d_in[3];
    const int* src = (const int*)d_in[4];
    const int* dst = (const int*)d_in[5];
    float* out = (float*)d_out;

    // workspace layout (~17.9 MB; poisoned every call — every buffer is
    // fully written before it is read)
    char* ws = (char*)d_ws;
    __half*         h2     = (__half*)(ws);                     // 6.4 MB
    unsigned*       packed = (unsigned*)(ws + 6400000);         // NBUCK*CAP*4 = 7.21 MB
    unsigned short* csr    = (unsigned short*)(ws + 13606912);  // NBUCK*CAP*2 = 3.6 MB
    int*            rowptr = (int*)(ws + 17210368);             // N*4
    int*            rowend = (int*)(ws + 17410368);             // N*4
    float*          norm   = (float*)(ws + 17610368);           // N*4
    int*            cursor = (int*)(ws + 17810368);             // NBUCK*4

    k_init     <<<1, 512, 0, stream>>>(cursor);
    k_bucket   <<<BBLOCKS, BTHREADS, 0, stream>>>(src, dst, cursor, packed);
    k_csrg     <<<NBUCK, 1024, 0, stream>>>(cursor, packed, x, W, csr, rowptr, rowend, norm, h2);
    k_aggregate<<<(N + 3) / 4, 256, 0, stream>>>(rowptr, rowend, csr, h2, norm, bias, out);
}